// Round 9
// baseline (265.328 us; speedup 1.0000x reference)
//
#include <hip/hip_runtime.h>
#include <hip/hip_bf16.h>

// DIAGNOSTIC ROUND: pair_add writes the (identical) output 5x so the dispatch
// exceeds the harness fill kernels' ~155us and surfaces in the top-5 profile
// with its FETCH_SIZE / WRITE_SIZE / hbm_gbps. Output is unchanged.

typedef float f4    __attribute__((ext_vector_type(4)));
typedef short s8    __attribute__((ext_vector_type(8)));   // 8 bf16 (4 VGPRs)
typedef float f32x4 __attribute__((ext_vector_type(4)));

static __device__ __forceinline__ short bf16_rne(float f) {
    unsigned u = __builtin_bit_cast(unsigned, f);
    u += 0x7FFFu + ((u >> 16) & 1u);
    return (short)(u >> 16);
}

// LDS-free MFMA GEMM: 512 blocks x 4 waves; each wave owns one 16x16 Y-tile.
__global__ __launch_bounds__(256) void gemm_mfma(const float* __restrict__ A,
                                                 const float* __restrict__ W,
                                                 float* __restrict__ Y) {
    const int tid = threadIdx.x;
    const int w = tid >> 6;          // wave 0..3
    const int l = tid & 63;
    const int rc = l & 15;           // A-row / B-col / C-col
    const int g  = l >> 4;           // k-group (8 floats each)
    const int m0 = blockIdx.x * 32 + (w >> 1) * 16;   // gridDim.x = 32
    const int o0 = blockIdx.y * 32 + (w & 1) * 16;    // gridDim.y = 16

    const float* __restrict__ ap = A + (m0 + rc) * 512 + g * 8;
    const float* __restrict__ wp = W + (o0 + rc) * 512 + g * 8;

    f32x4 acc = {0.f, 0.f, 0.f, 0.f};

    #pragma unroll 4
    for (int kk = 0; kk < 16; ++kk) {
        const f4 alo = *(const f4*)(ap + kk * 32);
        const f4 ahi = *(const f4*)(ap + kk * 32 + 4);
        const f4 blo = *(const f4*)(wp + kk * 32);
        const f4 bhi = *(const f4*)(wp + kk * 32 + 4);
        s8 af, bf;
        af[0] = bf16_rne(alo.x); af[1] = bf16_rne(alo.y);
        af[2] = bf16_rne(alo.z); af[3] = bf16_rne(alo.w);
        af[4] = bf16_rne(ahi.x); af[5] = bf16_rne(ahi.y);
        af[6] = bf16_rne(ahi.z); af[7] = bf16_rne(ahi.w);
        bf[0] = bf16_rne(blo.x); bf[1] = bf16_rne(blo.y);
        bf[2] = bf16_rne(blo.z); bf[3] = bf16_rne(blo.w);
        bf[4] = bf16_rne(bhi.x); bf[5] = bf16_rne(bhi.y);
        bf[6] = bf16_rne(bhi.z); bf[7] = bf16_rne(bhi.w);
        acc = __builtin_amdgcn_mfma_f32_16x16x32_bf16(af, bf, acc, 0, 0, 0);
    }

    // C/D layout (m89-verified): col = l&15, row = (l>>4)*4 + q
    #pragma unroll
    for (int q = 0; q < 4; ++q)
        Y[(m0 + g * 4 + q) * 512 + o0 + rc] = acc[q];
}

// R7 structure, but the j-loop runs NPASS times with identical values.
// asm memory clobber between passes prevents dead-store elimination.
__global__ __launch_bounds__(256) void pair_add(const f4* __restrict__ Y4,
                                                const f4* __restrict__ b4,
                                                f4* __restrict__ out4) {
    const int blk = blockIdx.x;          // b*128 + i, 0..1023
    const int t   = threadIdx.x;
    const int o4  = t & 127;             // 0..127 (128 f4 per row)
    const int jh  = t >> 7;              // 0 or 1

    const f4 yib = Y4[blk * 128 + o4] + b4[o4];
    const f4* __restrict__ Yb = Y4 + (blk >> 7) * (128 * 128);
    f4* __restrict__ orow = out4 + blk * (128 * 128);

    #pragma unroll 1
    for (int p = 0; p < 5; ++p) {
        #pragma unroll 4
        for (int j = jh; j < 128; j += 2) {
            const f4 r = yib + Yb[j * 128 + o4];
            __builtin_nontemporal_store(r, &orow[j * 128 + o4]);
        }
        asm volatile("" ::: "memory");
    }
}

extern "C" void kernel_launch(void* const* d_in, const int* in_sizes, int n_in,
                              void* d_out, int out_size, void* d_ws, size_t ws_size,
                              hipStream_t stream) {
    const float* L = (const float*)d_in[0];   // [8,128,512]
    const float* W = (const float*)d_in[1];   // [512,512]
    const float* b = (const float*)d_in[2];   // [512]
    float* out = (float*)d_out;               // [8,128,128,512]
    float* Y   = (float*)d_ws;                // [1024,512] scratch, 2 MiB

    gemm_mfma<<<dim3(32, 16), 256, 0, stream>>>(L, W, Y);
    pair_add<<<1024, 256, 0, stream>>>((const f4*)Y, (const f4*)b, (f4*)out);
    (void)in_sizes; (void)n_in; (void)out_size; (void)ws_size;
}

// Round 10
// 65.764 us; speedup vs baseline: 4.0346x; 4.0346x over previous
//
#include <hip/hip_runtime.h>
#include <hip/hip_bf16.h>

// out[b,i,j,o] = Y[b*128+i][o] + Y[b*128+j][o] + bias[o]
// where Y[m][o] = sum_h L[m][h] * W[o][h]   (M=1024, O=512, H=512)

typedef float f4    __attribute__((ext_vector_type(4)));
typedef short s8    __attribute__((ext_vector_type(8)));   // 8 bf16 (4 VGPRs)
typedef float f32x4 __attribute__((ext_vector_type(4)));

static __device__ __forceinline__ short bf16_rne(float f) {
    unsigned u = __builtin_bit_cast(unsigned, f);
    u += 0x7FFFu + ((u >> 16) & 1u);
    return (short)(u >> 16);
}

// LDS-free MFMA GEMM: 512 blocks x 4 waves; each wave owns one 16x16 Y-tile.
// (R9 diag: GEMM + launch overhead = 3.4 us total — done.)
__global__ __launch_bounds__(256) void gemm_mfma(const float* __restrict__ A,
                                                 const float* __restrict__ W,
                                                 float* __restrict__ Y) {
    const int tid = threadIdx.x;
    const int w = tid >> 6;          // wave 0..3
    const int l = tid & 63;
    const int rc = l & 15;           // A-row / B-col / C-col
    const int g  = l >> 4;           // k-group (8 floats each)
    const int m0 = blockIdx.x * 32 + (w >> 1) * 16;   // gridDim.x = 32
    const int o0 = blockIdx.y * 32 + (w & 1) * 16;    // gridDim.y = 16

    const float* __restrict__ ap = A + (m0 + rc) * 512 + g * 8;
    const float* __restrict__ wp = W + (o0 + rc) * 512 + g * 8;

    f32x4 acc = {0.f, 0.f, 0.f, 0.f};

    #pragma unroll 4
    for (int kk = 0; kk < 16; ++kk) {
        const f4 alo = *(const f4*)(ap + kk * 32);
        const f4 ahi = *(const f4*)(ap + kk * 32 + 4);
        const f4 blo = *(const f4*)(wp + kk * 32);
        const f4 bhi = *(const f4*)(wp + kk * 32 + 4);
        s8 af, bf;
        af[0] = bf16_rne(alo.x); af[1] = bf16_rne(alo.y);
        af[2] = bf16_rne(alo.z); af[3] = bf16_rne(alo.w);
        af[4] = bf16_rne(ahi.x); af[5] = bf16_rne(ahi.y);
        af[6] = bf16_rne(ahi.z); af[7] = bf16_rne(ahi.w);
        bf[0] = bf16_rne(blo.x); bf[1] = bf16_rne(blo.y);
        bf[2] = bf16_rne(blo.z); bf[3] = bf16_rne(blo.w);
        bf[4] = bf16_rne(bhi.x); bf[5] = bf16_rne(bhi.y);
        bf[6] = bf16_rne(bhi.z); bf[7] = bf16_rne(bhi.w);
        acc = __builtin_amdgcn_mfma_f32_16x16x32_bf16(af, bf, acc, 0, 0, 0);
    }

    // C/D layout (m89-verified): col = l&15, row = (l>>4)*4 + q
    #pragma unroll
    for (int q = 0; q < 4; ++q)
        Y[(m0 + g * 4 + q) * 512 + o0 + rc] = acc[q];
}

// One block per (b,i). PLAIN stores this round (R9 showed NT stream caps at
// 5.15 TB/s vs 6.9 TB/s for the plain-store fill kernels; reads are 8 MB/dispatch
// so the write path is everything).
__global__ __launch_bounds__(256) void pair_add(const f4* __restrict__ Y4,
                                                const f4* __restrict__ b4,
                                                f4* __restrict__ out4) {
    const int blk = blockIdx.x;          // b*128 + i, 0..1023
    const int t   = threadIdx.x;
    const int o4  = t & 127;             // 0..127 (128 f4 per row)
    const int jh  = t >> 7;              // 0 or 1

    const f4 yib = Y4[blk * 128 + o4] + b4[o4];
    const f4* __restrict__ Yb = Y4 + (blk >> 7) * (128 * 128);
    f4* __restrict__ orow = out4 + blk * (128 * 128);

    #pragma unroll 4
    for (int j = jh; j < 128; j += 2) {
        orow[j * 128 + o4] = yib + Yb[j * 128 + o4];
    }
}

extern "C" void kernel_launch(void* const* d_in, const int* in_sizes, int n_in,
                              void* d_out, int out_size, void* d_ws, size_t ws_size,
                              hipStream_t stream) {
    const float* L = (const float*)d_in[0];   // [8,128,512]
    const float* W = (const float*)d_in[1];   // [512,512]
    const float* b = (const float*)d_in[2];   // [512]
    float* out = (float*)d_out;               // [8,128,128,512]
    float* Y   = (float*)d_ws;                // [1024,512] scratch, 2 MiB

    gemm_mfma<<<dim3(32, 16), 256, 0, stream>>>(L, W, Y);
    pair_add<<<1024, 256, 0, stream>>>((const f4*)Y, (const f4*)b, (f4*)out);
    (void)in_sizes; (void)n_in; (void)out_size; (void)ws_size;
}

// Round 11
// 65.436 us; speedup vs baseline: 4.0548x; 1.0050x over previous
//
#include <hip/hip_runtime.h>
#include <hip/hip_bf16.h>

// out[b,i,j,o] = Y[b*128+i][o] + Y[b*128+j][o] + bias[o]
// where Y[m][o] = sum_h L[m][h] * W[o][h]   (M=1024, O=512, H=512)

typedef float f4    __attribute__((ext_vector_type(4)));
typedef short s8    __attribute__((ext_vector_type(8)));   // 8 bf16 (4 VGPRs)
typedef float f32x4 __attribute__((ext_vector_type(4)));

static __device__ __forceinline__ short bf16_rne(float f) {
    unsigned u = __builtin_bit_cast(unsigned, f);
    u += 0x7FFFu + ((u >> 16) & 1u);
    return (short)(u >> 16);
}

// LDS-free MFMA GEMM: 512 blocks x 4 waves; each wave owns one 16x16 Y-tile.
// (R9 diag: GEMM + launch overhead = 3.4 us total — done.)
__global__ __launch_bounds__(256) void gemm_mfma(const float* __restrict__ A,
                                                 const float* __restrict__ W,
                                                 float* __restrict__ Y) {
    const int tid = threadIdx.x;
    const int w = tid >> 6;          // wave 0..3
    const int l = tid & 63;
    const int rc = l & 15;           // A-row / B-col / C-col
    const int g  = l >> 4;           // k-group (8 floats each)
    const int m0 = blockIdx.x * 32 + (w >> 1) * 16;   // gridDim.x = 32
    const int o0 = blockIdx.y * 32 + (w & 1) * 16;    // gridDim.y = 16

    const float* __restrict__ ap = A + (m0 + rc) * 512 + g * 8;
    const float* __restrict__ wp = W + (o0 + rc) * 512 + g * 8;

    f32x4 acc = {0.f, 0.f, 0.f, 0.f};

    #pragma unroll 4
    for (int kk = 0; kk < 16; ++kk) {
        const f4 alo = *(const f4*)(ap + kk * 32);
        const f4 ahi = *(const f4*)(ap + kk * 32 + 4);
        const f4 blo = *(const f4*)(wp + kk * 32);
        const f4 bhi = *(const f4*)(wp + kk * 32 + 4);
        s8 af, bf;
        af[0] = bf16_rne(alo.x); af[1] = bf16_rne(alo.y);
        af[2] = bf16_rne(alo.z); af[3] = bf16_rne(alo.w);
        af[4] = bf16_rne(ahi.x); af[5] = bf16_rne(ahi.y);
        af[6] = bf16_rne(ahi.z); af[7] = bf16_rne(ahi.w);
        bf[0] = bf16_rne(blo.x); bf[1] = bf16_rne(blo.y);
        bf[2] = bf16_rne(blo.z); bf[3] = bf16_rne(blo.w);
        bf[4] = bf16_rne(bhi.x); bf[5] = bf16_rne(bhi.y);
        bf[6] = bf16_rne(bhi.z); bf[7] = bf16_rne(bhi.w);
        acc = __builtin_amdgcn_mfma_f32_16x16x32_bf16(af, bf, acc, 0, 0, 0);
    }

    // C/D layout (m89-verified): col = l&15, row = (l>>4)*4 + q
    #pragma unroll
    for (int q = 0; q < 4; ++q)
        Y[(m0 + g * 4 + q) * 512 + o0 + rc] = acc[q];
}

// 4096 blocks = (b*128+i) * 4 j-quarters -> 16 blocks/CU oversubscription so
// the scheduler backfills fast CUs (R9 showed 28% occupancy = ~2x skew with
// zero backfill at 1024 blocks). Phase 1: 17 loads into regs, wait once.
// Phase 2: pure PLAIN store burst (NT cost +6.4us, R10).
__global__ __launch_bounds__(256) void pair_add(const f4* __restrict__ Y4,
                                                const f4* __restrict__ b4,
                                                f4* __restrict__ out4) {
    const int blk = blockIdx.x;
    const int bi  = blk >> 2;            // b*128 + i
    const int jq  = blk & 3;             // j0 = jq*32
    const int t   = threadIdx.x;
    const int o4  = t & 127;             // 0..127
    const int jh  = t >> 7;              // 0 or 1

    const f4* __restrict__ Yb = Y4 + (bi >> 7) * (128 * 128);
    const int j0 = jq * 32 + jh;         // j = j0 + 2k

    f4 v[16];
    #pragma unroll
    for (int k = 0; k < 16; ++k)
        v[k] = Yb[(j0 + 2 * k) * 128 + o4];
    const f4 yib = Y4[bi * 128 + o4] + b4[o4];
    #pragma unroll
    for (int k = 0; k < 16; ++k)
        v[k] += yib;

    asm volatile("" ::: "memory");   // phase fence

    f4* __restrict__ orow = out4 + (size_t)bi * (128 * 128);
    #pragma unroll
    for (int k = 0; k < 16; ++k)
        orow[(j0 + 2 * k) * 128 + o4] = v[k];
}

extern "C" void kernel_launch(void* const* d_in, const int* in_sizes, int n_in,
                              void* d_out, int out_size, void* d_ws, size_t ws_size,
                              hipStream_t stream) {
    const float* L = (const float*)d_in[0];   // [8,128,512]
    const float* W = (const float*)d_in[1];   // [512,512]
    const float* b = (const float*)d_in[2];   // [512]
    float* out = (float*)d_out;               // [8,128,128,512]
    float* Y   = (float*)d_ws;                // [1024,512] scratch, 2 MiB

    gemm_mfma<<<dim3(32, 16), 256, 0, stream>>>(L, W, Y);
    pair_add<<<4096, 256, 0, stream>>>((const f4*)Y, (const f4*)b, (f4*)out);
    (void)in_sizes; (void)n_in; (void)out_size; (void)ws_size;
}